// Round 1
// baseline (13176.418 us; speedup 1.0000x reference)
//
#include <hip/hip_runtime.h>
#include <math.h>

#define TT 32
#define DD 64
#define NN 1024
#define VV 64
#define RR 4
#define HH 512
#define DINN 320   // D + R*V
#define G4 2048    // 4*H
#define NTHREADS 1024

__device__ __forceinline__ float sigf(float x) { return 1.0f / (1.0f + __expf(-x)); }
__device__ __forceinline__ float splus(float x) {
  return (x > 0.f) ? (x + log1pf(__expf(-x))) : log1pf(__expf(x));
}
__device__ __forceinline__ float dot4f(float4 a, float4 b) {
  return a.x * b.x + a.y * b.y + a.z * b.z + a.w * b.w;
}

// block-wide sum over 1024 threads; all threads must call; returns sum to all.
__device__ __forceinline__ float blk_sum(float v, float* red, int tid) {
  #pragma unroll
  for (int o = 32; o; o >>= 1) v += __shfl_xor(v, o);
  if ((tid & 63) == 0) red[tid >> 6] = v;
  __syncthreads();
  if (tid < 16) {
    float s = red[tid];
    #pragma unroll
    for (int o = 8; o; o >>= 1) s += __shfl_xor(s, o);
    if (tid == 0) red[16] = s;
  }
  __syncthreads();
  return red[16];
}

__global__ __launch_bounds__(NTHREADS, 1) void ntm_fwd(
    const float* __restrict__ x, const float* __restrict__ mem_bias,
    const float* __restrict__ h_bias, const float* __restrict__ c_bias,
    const float* __restrict__ W_ih, const float* __restrict__ W_hh,
    const float* __restrict__ b_ih, const float* __restrict__ b_hh,
    const float* __restrict__ read_W, const float* __restrict__ read_b,
    const float* __restrict__ write_W, const float* __restrict__ write_b,
    const float* __restrict__ read_init, const float* __restrict__ out_W,
    const float* __restrict__ out_b, float* __restrict__ out,
    float* __restrict__ wsbuf) {
  const int b = blockIdx.x;
  const int tid = threadIdx.x;
  const int lane = tid & 63;
  const int wave = tid >> 6;

  // persistent per-sequence state
  __shared__ float s_ws[8 * NN];                     // 32 KB shift-weight history
  __shared__ alignas(16) float s_scr2[2048];         // gates | (w_buf[0:1024], wg[1024:2048])
  __shared__ alignas(16) float s_h[HH];
  __shared__ float s_c[HH];
  __shared__ alignas(16) float s_fx[768];            // cx (320) | final_x (768)
  __shared__ float s_norm2[NN];
  __shared__ float s_redbuf[16 * 64];
  __shared__ alignas(16) float s_reads[RR * VV];
  __shared__ float s_or[72];
  __shared__ float s_ow[200];
  __shared__ alignas(16) float s_kb[VV];
  __shared__ alignas(16) float s_e[VV];
  __shared__ alignas(16) float s_a[VV];
  __shared__ float s_scal[8];
  __shared__ float s_red[24];

  float* memp = wsbuf + (size_t)b * (NN * VV);

  // ---- init (every call: deterministic) ----
  {
    const float4* mb4 = (const float4*)mem_bias;
    float4* m4 = (float4*)memp;
    for (int i = tid; i < NN * VV / 4; i += NTHREADS) m4[i] = mb4[i];
    for (int i = tid; i < HH; i += NTHREADS) { s_h[i] = h_bias[i]; s_c[i] = c_bias[i]; }
    for (int i = tid; i < RR * VV; i += NTHREADS) s_reads[i] = read_init[i];
    for (int i = tid; i < 8 * NN; i += NTHREADS) s_ws[i] = 0.0f;
  }
  __syncthreads();
  { // initial row norms of (mem + 1e-16)
    const float4* row = (const float4*)memp + tid * 16;
    float acc = 0.f;
    #pragma unroll 4
    for (int p = 0; p < 16; ++p) {
      float4 m = row[p];
      float a0 = m.x + 1e-16f, a1 = m.y + 1e-16f, a2 = m.z + 1e-16f, a3 = m.w + 1e-16f;
      acc += a0 * a0 + a1 * a1 + a2 * a2 + a3 * a3;
    }
    s_norm2[tid] = acc;
  }
  __syncthreads();

  for (int t = 0; t < TT; ++t) {
    // ---- contr_x = [x_t, reads] ----
    if (tid < DD) s_fx[tid] = x[((size_t)b * TT + t) * DD + tid];
    else if (tid < DINN) s_fx[tid] = s_reads[tid - DD];
    __syncthreads();

    // ---- LSTM gates GEMV: 2048 outputs, 2 per thread ----
    for (int j = tid; j < G4; j += NTHREADS) {
      const float4* wi = (const float4*)(W_ih + (size_t)j * DINN);
      const float4* wh = (const float4*)(W_hh + (size_t)j * HH);
      const float4* cx4 = (const float4*)s_fx;
      const float4* h4 = (const float4*)s_h;
      float acc = b_ih[j] + b_hh[j];
      #pragma unroll 4
      for (int p = 0; p < DINN / 4; ++p) acc += dot4f(wi[p], cx4[p]);
      #pragma unroll 4
      for (int p = 0; p < HH / 4; ++p) acc += dot4f(wh[p], h4[p]);
      s_scr2[j] = acc;
    }
    __syncthreads();
    // ---- LSTM elementwise ----
    if (tid < HH) {
      float gi = s_scr2[tid], gf = s_scr2[HH + tid];
      float gg = s_scr2[2 * HH + tid], go = s_scr2[3 * HH + tid];
      float cn = sigf(gf) * s_c[tid] + sigf(gi) * tanhf(gg);
      float hn = sigf(go) * tanhf(cn);
      s_c[tid] = cn;
      s_h[tid] = hn;   // co
    }
    __syncthreads();

    for (int hd = 0; hd < RR; ++hd) {
      // ======== read head ========
      // o_r = co @ read_W[hd].T + read_b[hd]  (70 outputs, 8 lanes each)
      if (tid < 560) {
        int j = tid >> 3, sub = tid & 7;
        const float4* wr = (const float4*)(read_W + ((size_t)hd * 70 + j) * HH + sub * 64);
        const float4* h4 = (const float4*)s_h + sub * 16;
        float acc = 0.f;
        #pragma unroll 4
        for (int p = 0; p < 16; ++p) acc += dot4f(wr[p], h4[p]);
        acc += __shfl_xor(acc, 1); acc += __shfl_xor(acc, 2); acc += __shfl_xor(acc, 4);
        if (sub == 0) s_or[j] = acc + read_b[hd * 70 + j];
      }
      __syncthreads();
      // key + scalars
      if (tid < VV) {
        float kv = s_or[tid] + 1e-16f;
        s_kb[tid] = kv;
        float sq = kv * kv;
        #pragma unroll
        for (int o = 32; o; o >>= 1) sq += __shfl_xor(sq, o);
        if (tid == 0) {
          float nb = fmaxf(sqrtf(sq), 1e-8f);
          float beta = splus(s_or[64]);
          float g = sigf(s_or[65]);
          float a0 = s_or[66], a1 = s_or[67], a2 = s_or[68];
          float mx = fmaxf(a0, fmaxf(a1, a2));
          float e0 = __expf(a0 - mx), e1 = __expf(a1 - mx), e2 = __expf(a2 - mx);
          float inv = 1.0f / (e0 + e1 + e2);
          s_scal[0] = beta / nb; s_scal[1] = g;
          s_scal[2] = e0 * inv; s_scal[3] = e1 * inv; s_scal[4] = e2 * inv;
          s_scal[5] = 1.0f + splus(s_or[69]);
        }
      }
      __syncthreads();
      { // addressing (slot 2*hd)
        const float4* row = (const float4*)memp + tid * 16;
        const float4* kb4 = (const float4*)s_kb;
        float dotv = 0.f;
        #pragma unroll 4
        for (int p = 0; p < 16; ++p) {
          float4 m = row[p], k = kb4[p];
          dotv += (m.x + 1e-16f) * k.x + (m.y + 1e-16f) * k.y +
                  (m.z + 1e-16f) * k.z + (m.w + 1e-16f) * k.w;
        }
        float na = fmaxf(sqrtf(s_norm2[tid]), 1e-8f);
        float z = s_scal[0] * dotv / na;     // beta*cos (nb folded into scal0)
        float e = __expf(z);                  // no max-sub needed: |z| <= beta (small)
        float S = blk_sum(e, s_red, tid);
        float wc = e / S;
        float g = s_scal[1];
        float wgv = g * wc + (1.0f - g) * s_ws[(2 * hd) * NN + tid];
        s_scr2[1024 + tid] = wgv;
      }
      __syncthreads();
      {
        float* wg = s_scr2 + 1024;
        float wsn = s_scal[2] * wg[(tid + 1023) & 1023] + s_scal[3] * wg[tid] +
                    s_scal[4] * wg[(tid + 1) & 1023];
        float wp = __expf(s_scal[5] * __logf(wsn));
        float Z = blk_sum(wp, s_red, tid);
        float wfin = wp / (Z + 1e-16f);
        s_scr2[tid] = wfin;                 // w_buf
        s_ws[(2 * hd) * NN + tid] = wfin;
      }
      __syncthreads();
      { // read: reads[hd][v] = sum_n w[n]*mem[n][v]; wave handles 64 rows, coalesced
        float acc = 0.f;
        int base = wave * 64;
        for (int r = 0; r < 64; ++r) {
          float wn = s_scr2[base + r];
          acc += wn * memp[(size_t)(base + r) * VV + lane];
        }
        s_redbuf[wave * 64 + lane] = acc;
      }
      __syncthreads();
      if (tid < VV) {
        float s = 0.f;
        #pragma unroll
        for (int w2 = 0; w2 < 16; ++w2) s += s_redbuf[w2 * 64 + tid];
        s_reads[hd * VV + tid] = s;
      }
      // ======== write head ========
      // o_w = co @ write_W[hd].T + write_b[hd]  (198 outputs, 4 lanes each)
      if (tid < 792) {
        int j = tid >> 2, sub = tid & 3;
        const float4* ww = (const float4*)(write_W + ((size_t)hd * 198 + j) * HH + sub * 128);
        const float4* h4 = (const float4*)s_h + sub * 32;
        float acc = 0.f;
        #pragma unroll 4
        for (int p = 0; p < 32; ++p) acc += dot4f(ww[p], h4[p]);
        acc += __shfl_xor(acc, 1); acc += __shfl_xor(acc, 2);
        if (sub == 0) s_ow[j] = acc + write_b[hd * 198 + j];
      }
      __syncthreads();
      if (tid < VV) {
        s_e[tid] = sigf(s_ow[70 + tid]);
        s_a[tid] = s_ow[134 + tid];
        float kv = s_ow[tid] + 1e-16f;
        s_kb[tid] = kv;
        float sq = kv * kv;
        #pragma unroll
        for (int o = 32; o; o >>= 1) sq += __shfl_xor(sq, o);
        if (tid == 0) {
          float nb = fmaxf(sqrtf(sq), 1e-8f);
          float beta = splus(s_ow[64]);
          float g = sigf(s_ow[65]);
          float a0 = s_ow[66], a1 = s_ow[67], a2 = s_ow[68];
          float mx = fmaxf(a0, fmaxf(a1, a2));
          float e0 = __expf(a0 - mx), e1 = __expf(a1 - mx), e2 = __expf(a2 - mx);
          float inv = 1.0f / (e0 + e1 + e2);
          s_scal[0] = beta / nb; s_scal[1] = g;
          s_scal[2] = e0 * inv; s_scal[3] = e1 * inv; s_scal[4] = e2 * inv;
          s_scal[5] = 1.0f + splus(s_ow[69]);
        }
      }
      __syncthreads();
      { // addressing (slot 2*hd+1)
        const float4* row = (const float4*)memp + tid * 16;
        const float4* kb4 = (const float4*)s_kb;
        float dotv = 0.f;
        #pragma unroll 4
        for (int p = 0; p < 16; ++p) {
          float4 m = row[p], k = kb4[p];
          dotv += (m.x + 1e-16f) * k.x + (m.y + 1e-16f) * k.y +
                  (m.z + 1e-16f) * k.z + (m.w + 1e-16f) * k.w;
        }
        float na = fmaxf(sqrtf(s_norm2[tid]), 1e-8f);
        float z = s_scal[0] * dotv / na;
        float e = __expf(z);
        float S = blk_sum(e, s_red, tid);
        float wc = e / S;
        float g = s_scal[1];
        float wgv = g * wc + (1.0f - g) * s_ws[(2 * hd + 1) * NN + tid];
        s_scr2[1024 + tid] = wgv;
      }
      __syncthreads();
      {
        float* wg = s_scr2 + 1024;
        float wsn = s_scal[2] * wg[(tid + 1023) & 1023] + s_scal[3] * wg[tid] +
                    s_scal[4] * wg[(tid + 1) & 1023];
        float wp = __expf(s_scal[5] * __logf(wsn));
        float Z = blk_sum(wp, s_red, tid);
        float wfin = wp / (Z + 1e-16f);
        s_scr2[tid] = wfin;                 // w2
        s_ws[(2 * hd + 1) * NN + tid] = wfin;
      }
      __syncthreads();
      { // erase/add write + recompute row norm
        float w2n = s_scr2[tid];
        float4* row = (float4*)memp + tid * 16;
        const float4* e4 = (const float4*)s_e;
        const float4* a4 = (const float4*)s_a;
        float nacc = 0.f;
        #pragma unroll 4
        for (int p = 0; p < 16; ++p) {
          float4 m = row[p], ev = e4[p], av = a4[p];
          m.x = m.x * (1.0f - w2n * ev.x) + w2n * av.x;
          m.y = m.y * (1.0f - w2n * ev.y) + w2n * av.y;
          m.z = m.z * (1.0f - w2n * ev.z) + w2n * av.z;
          m.w = m.w * (1.0f - w2n * ev.w) + w2n * av.w;
          float t0 = m.x + 1e-16f, t1 = m.y + 1e-16f;
          float t2 = m.z + 1e-16f, t3 = m.w + 1e-16f;
          nacc += t0 * t0 + t1 * t1 + t2 * t2 + t3 * t3;
          row[p] = m;
        }
        s_norm2[tid] = nacc;
      }
      __syncthreads();
    } // heads

    // ---- output: y = sigmoid([co, reads] @ out_W.T + out_b) ----
    if (tid < HH) s_fx[tid] = s_h[tid];
    else if (tid < 768) s_fx[tid] = s_reads[tid - HH];
    __syncthreads();
    if (tid < 512) {
      int j = tid >> 3, sub = tid & 7;
      const float4* wo = (const float4*)(out_W + (size_t)j * 768 + sub * 96);
      const float4* f4 = (const float4*)s_fx + sub * 24;
      float acc = 0.f;
      #pragma unroll 4
      for (int p = 0; p < 24; ++p) acc += dot4f(wo[p], f4[p]);
      acc += __shfl_xor(acc, 1); acc += __shfl_xor(acc, 2); acc += __shfl_xor(acc, 4);
      if (sub == 0) out[((size_t)b * TT + t) * DD + j] = sigf(acc + out_b[j]);
    }
    __syncthreads();
  } // t
}

extern "C" void kernel_launch(void* const* d_in, const int* in_sizes, int n_in,
                              void* d_out, int out_size, void* d_ws, size_t ws_size,
                              hipStream_t stream) {
  ntm_fwd<<<dim3(64), dim3(NTHREADS), 0, stream>>>(
      (const float*)d_in[0], (const float*)d_in[1], (const float*)d_in[2],
      (const float*)d_in[3], (const float*)d_in[4], (const float*)d_in[5],
      (const float*)d_in[6], (const float*)d_in[7], (const float*)d_in[8],
      (const float*)d_in[9], (const float*)d_in[10], (const float*)d_in[11],
      (const float*)d_in[12], (const float*)d_in[13], (const float*)d_in[14],
      (float*)d_out, (float*)d_ws);
}

// Round 2
// 9073.074 us; speedup vs baseline: 1.4523x; 1.4523x over previous
//
#include <hip/hip_runtime.h>
#include <math.h>

#define TT 32
#define DD 64
#define NN 1024
#define VV 64
#define RR 4
#define HH 512
#define DINN 320   // D + R*V
#define NTHREADS 1024

typedef unsigned int uint_t;
typedef unsigned short ushort_t;

__device__ __forceinline__ float sigf(float x) { return 1.0f / (1.0f + __expf(-x)); }
__device__ __forceinline__ float splus(float x) {
  return (x > 0.f) ? (x + log1pf(__expf(-x))) : log1pf(__expf(x));
}
__device__ __forceinline__ float dot4f(float4 a, float4 b) {
  return a.x * b.x + a.y * b.y + a.z * b.z + a.w * b.w;
}
// 8 bf16 weights (as uint4) dotted with 8 fp32 activations
__device__ __forceinline__ float dot8bf(uint4 w, float4 ha, float4 hb) {
  float s;
  s  = __uint_as_float(w.x << 16) * ha.x + __uint_as_float(w.x & 0xffff0000u) * ha.y;
  s += __uint_as_float(w.y << 16) * ha.z + __uint_as_float(w.y & 0xffff0000u) * ha.w;
  s += __uint_as_float(w.z << 16) * hb.x + __uint_as_float(w.z & 0xffff0000u) * hb.y;
  s += __uint_as_float(w.w << 16) * hb.z + __uint_as_float(w.w & 0xffff0000u) * hb.w;
  return s;
}

// addressing: all 1024 threads. Consumes oarr[0..69] (key+scalars), slot history,
// mem row `tid`. Leaves final w in s_scr[tid] and s_ws[slot*NN+tid].
// 3 internal syncs. If easrc != nullptr, lanes 960..1023 also produce s_e/s_a.
__device__ __forceinline__ void addressing(
    const float* __restrict__ oarr, int slot, const float* __restrict__ memrow,
    float* __restrict__ s_ws, float* __restrict__ s_scr,
    const float* __restrict__ s_norm2, float* __restrict__ s_red,
    const float* easrc, float* __restrict__ s_e, float* __restrict__ s_a,
    int tid, int lane, int wave) {
  float dotv = 0.f, kk = 0.f;
  const float4* row = (const float4*)memrow;
  const float4* o4 = (const float4*)oarr;
  #pragma unroll 4
  for (int p = 0; p < 16; ++p) {
    float4 m = row[p]; float4 o = o4[p];
    float k0 = o.x + 1e-16f, k1 = o.y + 1e-16f, k2 = o.z + 1e-16f, k3 = o.w + 1e-16f;
    dotv += (m.x + 1e-16f) * k0 + (m.y + 1e-16f) * k1 +
            (m.z + 1e-16f) * k2 + (m.w + 1e-16f) * k3;
    kk += k0 * k0 + k1 * k1 + k2 * k2 + k3 * k3;
  }
  // redundant per-thread scalars (cheap; saves a phase+sync)
  float nb = fmaxf(sqrtf(kk), 1e-8f);
  float beta = splus(oarr[64]);
  float g = sigf(oarr[65]);
  float a0 = oarr[66], a1 = oarr[67], a2 = oarr[68];
  float mx = fmaxf(a0, fmaxf(a1, a2));
  float e0 = __expf(a0 - mx), e1 = __expf(a1 - mx), e2 = __expf(a2 - mx);
  float sinv = 1.0f / (e0 + e1 + e2);
  float s0 = e0 * sinv, s1 = e1 * sinv, s2 = e2 * sinv;
  float gamma = 1.0f + splus(oarr[69]);
  float na = fmaxf(sqrtf(s_norm2[tid]), 1e-8f);
  float z = beta * dotv / (na * nb);
  float ee = __expf(z);                    // no max-sub: |z| <= beta (small)
  float v = ee;
  #pragma unroll
  for (int o = 32; o; o >>= 1) v += __shfl_xor(v, o);
  if (lane == 0) s_red[wave] = v;
  __syncthreads();                         // (A)
  if (easrc && tid >= 960) {               // idle-ish lanes prep erase/add vecs
    int q = tid - 960;
    s_e[q] = sigf(easrc[q]);
    s_a[q] = easrc[64 + q];
  }
  float S = 0.f;
  #pragma unroll
  for (int w = 0; w < 16; ++w) S += s_red[w];
  float wc = ee / S;
  float wgv = g * wc + (1.0f - g) * s_ws[slot * NN + tid];
  s_scr[1024 + tid] = wgv;
  __syncthreads();                         // (B)
  const float* wg = s_scr + 1024;
  float wsn = s0 * wg[(tid + 1023) & 1023] + s1 * wg[tid] + s2 * wg[(tid + 1) & 1023];
  float wp = __expf(gamma * __logf(wsn));
  v = wp;
  #pragma unroll
  for (int o = 32; o; o >>= 1) v += __shfl_xor(v, o);
  if (lane == 0) s_red[wave] = v;
  __syncthreads();                         // (C)
  float Z = 0.f;
  #pragma unroll
  for (int w = 0; w < 16; ++w) Z += s_red[w];
  float wfin = wp / (Z + 1e-16f);
  s_scr[tid] = wfin;                       // same-thread readable immediately
  s_ws[slot * NN + tid] = wfin;
}

__global__ __launch_bounds__(NTHREADS, 1) void ntm_fwd(
    const float* __restrict__ x, const float* __restrict__ mem_bias,
    const float* __restrict__ h_bias, const float* __restrict__ c_bias,
    const float* __restrict__ gbias,
    const ushort_t* __restrict__ bWih, const ushort_t* __restrict__ bWhh,
    const ushort_t* __restrict__ brW, const ushort_t* __restrict__ bwW,
    const float* __restrict__ read_b, const float* __restrict__ write_b,
    const float* __restrict__ read_init,
    const float* __restrict__ out_W, const float* __restrict__ out_b,
    float* __restrict__ out, float* __restrict__ wsmem) {
  const int b = blockIdx.x;
  const int tid = threadIdx.x;
  const int lane = tid & 63;
  const int wave = tid >> 6;

  __shared__ float s_ws[8 * NN];                 // shift-weight history (32 KB)
  __shared__ alignas(16) float s_scr[2048];      // gates | w[0:1024], wg[1024:2048]
  __shared__ alignas(16) float s_h[HH];
  __shared__ float s_c[HH];
  __shared__ alignas(16) float s_fx[768];        // cx (320) | final_x (768)
  __shared__ float s_norm2[NN];
  __shared__ float s_redbuf[16 * 64];
  __shared__ alignas(16) float s_reads[RR * VV];
  __shared__ alignas(16) float s_or[72];
  __shared__ alignas(16) float s_ow[200];
  __shared__ alignas(16) float s_e[VV];
  __shared__ alignas(16) float s_a[VV];
  __shared__ float s_red[16];

  float* memp = wsmem + (size_t)b * (NN * VV);

  { // init
    const float4* mb4 = (const float4*)mem_bias;
    float4* m4 = (float4*)memp;
    for (int i = tid; i < NN * VV / 4; i += NTHREADS) m4[i] = mb4[i];
    for (int i = tid; i < HH; i += NTHREADS) { s_h[i] = h_bias[i]; s_c[i] = c_bias[i]; }
    for (int i = tid; i < RR * VV; i += NTHREADS) s_reads[i] = read_init[i];
    for (int i = tid; i < 8 * NN; i += NTHREADS) s_ws[i] = 0.0f;
  }
  __syncthreads();
  { // initial row norms of (mem + 1e-16)
    const float4* row = (const float4*)memp + tid * 16;
    float acc = 0.f;
    #pragma unroll 4
    for (int p = 0; p < 16; ++p) {
      float4 m = row[p];
      float t0 = m.x + 1e-16f, t1 = m.y + 1e-16f, t2 = m.z + 1e-16f, t3 = m.w + 1e-16f;
      acc += t0 * t0 + t1 * t1 + t2 * t2 + t3 * t3;
    }
    s_norm2[tid] = acc;
  }
  __syncthreads();

  for (int t = 0; t < TT; ++t) {
    // phase0: contr_x = [x_t, reads]
    if (tid < DD) s_fx[tid] = x[((size_t)b * TT + t) * DD + tid];
    else if (tid < DINN) s_fx[tid] = s_reads[tid - DD];
    __syncthreads();

    // phase1: gates GEMV, bf16 weights, 2 rows/thread
    {
      const uint4* wi0 = (const uint4*)(bWih + (size_t)tid * DINN);
      const uint4* wi1 = (const uint4*)(bWih + (size_t)(tid + 1024) * DINN);
      const uint4* wh0 = (const uint4*)(bWhh + (size_t)tid * HH);
      const uint4* wh1 = (const uint4*)(bWhh + (size_t)(tid + 1024) * HH);
      const float4* cx = (const float4*)s_fx;
      const float4* h4 = (const float4*)s_h;
      float acc0 = gbias[tid], acc1 = gbias[tid + 1024];
      #pragma unroll 4
      for (int p = 0; p < DINN / 8; ++p) {   // 40
        float4 ha = cx[2 * p], hb = cx[2 * p + 1];
        acc0 += dot8bf(wi0[p], ha, hb);
        acc1 += dot8bf(wi1[p], ha, hb);
      }
      #pragma unroll 4
      for (int p = 0; p < HH / 8; ++p) {     // 64
        float4 ha = h4[2 * p], hb = h4[2 * p + 1];
        acc0 += dot8bf(wh0[p], ha, hb);
        acc1 += dot8bf(wh1[p], ha, hb);
      }
      s_scr[tid] = acc0;
      s_scr[tid + 1024] = acc1;
    }
    __syncthreads();

    // phase2: LSTM elementwise
    if (tid < HH) {
      float gi = s_scr[tid], gf = s_scr[HH + tid];
      float gg = s_scr[2 * HH + tid], go = s_scr[3 * HH + tid];
      float cn = sigf(gf) * s_c[tid] + sigf(gi) * tanhf(gg);
      float hn = sigf(go) * tanhf(cn);
      s_c[tid] = cn;
      s_h[tid] = hn;
    }
    __syncthreads();

    for (int hd = 0; hd < RR; ++hd) {
      // read GEMV: 70 outputs x 8 sublanes, interleaved layout (conflict-free)
      if (tid < 560) {
        int j = tid >> 3, sub = tid & 7;
        const uint4* wr = (const uint4*)(brW + (((size_t)hd * 70 + j) << 9));
        const float4* h4 = (const float4*)s_h;
        float acc = 0.f;
        #pragma unroll
        for (int p = 0; p < 8; ++p) {
          int o = p * 16 + sub * 2;
          acc += dot8bf(wr[p * 8 + sub], h4[o], h4[o + 1]);
        }
        acc += __shfl_xor(acc, 1); acc += __shfl_xor(acc, 2); acc += __shfl_xor(acc, 4);
        if (sub == 0) s_or[j] = acc + read_b[hd * 70 + j];
      }
      __syncthreads();

      addressing(s_or, 2 * hd, memp + (size_t)tid * VV, s_ws, s_scr, s_norm2,
                 s_red, nullptr, s_e, s_a, tid, lane, wave);
      __syncthreads();   // w visible cross-thread for einsum

      { // read einsum partials: wave handles 64 rows, lane = column (coalesced)
        float acc = 0.f;
        int base = wave * 64;
        #pragma unroll 8
        for (int r = 0; r < 64; ++r)
          acc += s_scr[base + r] * memp[(size_t)(base + r) * VV + lane];
        s_redbuf[wave * 64 + lane] = acc;
      }
      __syncthreads();

      // write GEMV (198 x 4 sublanes) + read-combine on idle wave 15
      if (tid < 792) {
        int j = tid >> 2, sub = tid & 3;
        const uint4* ww = (const uint4*)(bwW + (((size_t)hd * 198 + j) << 9));
        const float4* h4 = (const float4*)s_h;
        float acc = 0.f;
        #pragma unroll
        for (int p = 0; p < 16; ++p) {
          int o = p * 8 + sub * 2;
          acc += dot8bf(ww[p * 4 + sub], h4[o], h4[o + 1]);
        }
        acc += __shfl_xor(acc, 1); acc += __shfl_xor(acc, 2);
        if (sub == 0) s_ow[j] = acc + write_b[hd * 198 + j];
      }
      if (tid >= 960) {
        int q = tid - 960;
        float s = 0.f;
        #pragma unroll
        for (int w = 0; w < 16; ++w) s += s_redbuf[w * 64 + q];
        s_reads[hd * VV + q] = s;
      }
      __syncthreads();

      addressing(s_ow, 2 * hd + 1, memp + (size_t)tid * VV, s_ws, s_scr, s_norm2,
                 s_red, s_ow + 70, s_e, s_a, tid, lane, wave);

      { // erase/add + norm recompute; w2 is same-thread, e/a synced inside addressing
        float w2n = s_scr[tid];
        float4* rowm = (float4*)(memp + (size_t)tid * VV);
        const float4* e4 = (const float4*)s_e;
        const float4* a4 = (const float4*)s_a;
        float nacc = 0.f;
        #pragma unroll 4
        for (int p = 0; p < 16; ++p) {
          float4 m = rowm[p], ev = e4[p], av = a4[p];
          m.x = m.x * (1.0f - w2n * ev.x) + w2n * av.x;
          m.y = m.y * (1.0f - w2n * ev.y) + w2n * av.y;
          m.z = m.z * (1.0f - w2n * ev.z) + w2n * av.z;
          m.w = m.w * (1.0f - w2n * ev.w) + w2n * av.w;
          float t0 = m.x + 1e-16f, t1 = m.y + 1e-16f;
          float t2 = m.z + 1e-16f, t3 = m.w + 1e-16f;
          nacc += t0 * t0 + t1 * t1 + t2 * t2 + t3 * t3;
          rowm[p] = m;
        }
        s_norm2[tid] = nacc;
      }
      // no sync: next phase touches disjoint data; mem/norm re-read same-thread first
    } // heads

    // final_x = [co, reads] (erase of hd=3 merged into this phase)
    if (tid < 768) s_fx[tid] = (tid < HH) ? s_h[tid] : s_reads[tid - HH];
    __syncthreads();

    // out GEMV (fp32 weights; interleaved sublanes)
    if (tid < 512) {
      int j = tid >> 3, sub = tid & 7;
      const float4* wo = (const float4*)(out_W + (size_t)j * 768);
      const float4* f4 = (const float4*)s_fx;
      float acc = 0.f;
      #pragma unroll
      for (int p = 0; p < 24; ++p) acc += dot4f(wo[p * 8 + sub], f4[p * 8 + sub]);
      acc += __shfl_xor(acc, 1); acc += __shfl_xor(acc, 2); acc += __shfl_xor(acc, 4);
      if (sub == 0) out[((size_t)b * TT + t) * DD + j] = sigf(acc + out_b[j]);
    }
    __syncthreads();
  } // t
}

// ---- weight pre-conversion (runs every launch; deterministic) ----
__device__ __forceinline__ ushort_t bfr(float f) {
  uint_t u = __float_as_uint(f);
  return (ushort_t)((u + 0x7fffu + ((u >> 16) & 1u)) >> 16);
}
__global__ void f2bf_kernel(const float4* __restrict__ src, ushort4* __restrict__ dst, int n4) {
  int i = blockIdx.x * 256 + threadIdx.x;
  if (i < n4) {
    float4 v = src[i];
    ushort4 o;
    o.x = bfr(v.x); o.y = bfr(v.y); o.z = bfr(v.z); o.w = bfr(v.w);
    dst[i] = o;
  }
}
__global__ void bias_kernel(const float* __restrict__ bi, const float* __restrict__ bh,
                            float* __restrict__ o) {
  int i = blockIdx.x * 256 + threadIdx.x;
  if (i < 2048) o[i] = bi[i] + bh[i];
}

extern "C" void kernel_launch(void* const* d_in, const int* in_sizes, int n_in,
                              void* d_out, int out_size, void* d_ws, size_t ws_size,
                              hipStream_t stream) {
  char* ws = (char*)d_ws;
  float* memws = (float*)ws;                       // 64*1024*64*4 = 16,777,216 B
  ushort_t* bWih = (ushort_t*)(ws + 16777216);     // 2048*320*2  = 1,310,720
  ushort_t* bWhh = (ushort_t*)(ws + 18087936);     // 2048*512*2  = 2,097,152
  ushort_t* brW  = (ushort_t*)(ws + 20185088);     // 4*70*512*2  =   286,720
  ushort_t* bwW  = (ushort_t*)(ws + 20471808);     // 4*198*512*2 =   811,008
  float* gbias   = (float*)(ws + 21282816);        // 2048*4      =     8,192

  const int nWih = 2048 * DINN, nWhh = 2048 * HH, nrW = RR * 70 * HH, nwW = RR * 198 * HH;
  f2bf_kernel<<<(nWih / 4 + 255) / 256, 256, 0, stream>>>((const float4*)d_in[4], (ushort4*)bWih, nWih / 4);
  f2bf_kernel<<<(nWhh / 4 + 255) / 256, 256, 0, stream>>>((const float4*)d_in[5], (ushort4*)bWhh, nWhh / 4);
  f2bf_kernel<<<(nrW / 4 + 255) / 256, 256, 0, stream>>>((const float4*)d_in[8], (ushort4*)brW, nrW / 4);
  f2bf_kernel<<<(nwW / 4 + 255) / 256, 256, 0, stream>>>((const float4*)d_in[10], (ushort4*)bwW, nwW / 4);
  bias_kernel<<<8, 256, 0, stream>>>((const float*)d_in[6], (const float*)d_in[7], gbias);

  ntm_fwd<<<dim3(64), dim3(NTHREADS), 0, stream>>>(
      (const float*)d_in[0], (const float*)d_in[1], (const float*)d_in[2],
      (const float*)d_in[3], gbias, bWih, bWhh, brW, bwW,
      (const float*)d_in[9], (const float*)d_in[11], (const float*)d_in[12],
      (const float*)d_in[13], (const float*)d_in[14],
      (float*)d_out, memws);
}